// Round 1
// baseline (96.934 us; speedup 1.0000x reference)
//
#include <hip/hip_runtime.h>

#define B 4
#define F 128
#define E 3000
#define T 6000
#define K 16      // max stored nonzeros per output column (Poisson(2) tail: P(>=16) ~ 5e-10)
#define ECHUNK 50 // e-rows per scan block

// ---------------------------------------------------------------------------
// Pass 1: scan unroll_mat (B,E,T), record nonzero e-indices per (b,t) column.
// Coalesced float4 reads of consecutive t. Binary matrix -> nonzero == 1.0.
// ---------------------------------------------------------------------------
__global__ void unpool_scan_kernel(const float* __restrict__ unroll,
                                   int* __restrict__ counts,
                                   int* __restrict__ idx) {
    const int b  = blockIdx.z;
    const int e0 = blockIdx.y * ECHUNK;
    const int t4 = (blockIdx.x * blockDim.x + threadIdx.x) * 4;
    if (t4 >= T) return;

    const float* base = unroll + (size_t)b * E * T;
    int* cbase = counts + b * T;
    int* ibase = idx + (size_t)b * T * K;

    for (int e = e0; e < e0 + ECHUNK; ++e) {
        const float4 v = *reinterpret_cast<const float4*>(base + (size_t)e * T + t4);
        if (v.x != 0.0f) { int t = t4 + 0; int c = atomicAdd(&cbase[t], 1); if (c < K) ibase[(size_t)t * K + c] = e; }
        if (v.y != 0.0f) { int t = t4 + 1; int c = atomicAdd(&cbase[t], 1); if (c < K) ibase[(size_t)t * K + c] = e; }
        if (v.z != 0.0f) { int t = t4 + 2; int c = atomicAdd(&cbase[t], 1); if (c < K) ibase[(size_t)t * K + c] = e; }
        if (v.w != 0.0f) { int t = t4 + 3; int c = atomicAdd(&cbase[t], 1); if (c < K) ibase[(size_t)t * K + c] = e; }
    }
}

// ---------------------------------------------------------------------------
// Pass 2: out[b,f,t] = (1/occ[b,t]) * sum_k features[b,f,e_k]
// 256 threads: t_local = tid & 31 (32 t per block), f_group = tid >> 5 (8
// groups), each thread does 16 f values. Writes coalesced over t.
// ---------------------------------------------------------------------------
__global__ void unpool_gather_kernel(const float* __restrict__ features,
                                     const float* __restrict__ occ,
                                     const float* __restrict__ unroll,
                                     const int* __restrict__ counts,
                                     const int* __restrict__ idx,
                                     float* __restrict__ out) {
    const int b = blockIdx.y;
    const int t = blockIdx.x * 32 + (threadIdx.x & 31);
    const int fg = threadIdx.x >> 5; // 0..7
    if (t >= T) return;

    const int c = counts[b * T + t];
    const float inv = 1.0f / occ[b * T + t];
    const float* fb = features + (size_t)b * F * E;
    float* ob = out + (size_t)b * F * T;

    if (c <= K) {
        // Load index list into registers (fully unrolled -> no scratch).
        // Entries beyond c are stale/garbage but never used (guarded below).
        int es[K];
        const int* ip = idx + ((size_t)b * T + t) * K;
#pragma unroll
        for (int k = 0; k < K; ++k) es[k] = ip[k];

        for (int f = fg; f < F; f += 8) {
            float acc = 0.0f;
#pragma unroll
            for (int k = 0; k < K; ++k) {
                if (k < c) acc += fb[(size_t)f * E + es[k]];
            }
            ob[(size_t)f * T + t] = acc * inv;
        }
    } else {
        // Astronomically rare overflow: exact rescan of this column.
        for (int f = fg; f < F; f += 8) {
            float acc = 0.0f;
            for (int e = 0; e < E; ++e) {
                if (unroll[((size_t)b * E + e) * T + t] != 0.0f)
                    acc += fb[(size_t)f * E + e];
            }
            ob[(size_t)f * T + t] = acc * inv;
        }
    }
}

// ---------------------------------------------------------------------------
// Dense fallback (only if workspace is too small — slow but exact).
// ---------------------------------------------------------------------------
__global__ void unpool_dense_fallback(const float* __restrict__ features,
                                      const float* __restrict__ unroll,
                                      const float* __restrict__ occ,
                                      float* __restrict__ out) {
    const int b = blockIdx.z;
    const int f = blockIdx.y;
    const int t = blockIdx.x * 64 + threadIdx.x;
    if (t >= T) return;
    const float* frow = features + ((size_t)b * F + f) * E;
    const float* ub = unroll + (size_t)b * E * T;
    float acc = 0.0f;
    for (int e = 0; e < E; ++e) acc += frow[e] * ub[(size_t)e * T + t];
    out[((size_t)b * F + f) * T + t] = acc / occ[b * T + t];
}

extern "C" void kernel_launch(void* const* d_in, const int* in_sizes, int n_in,
                              void* d_out, int out_size, void* d_ws, size_t ws_size,
                              hipStream_t stream) {
    const float* features = (const float*)d_in[0];   // (B,F,E) fp32
    const float* unroll   = (const float*)d_in[1];   // (B,E,T) fp32 (binary)
    const float* occ      = (const float*)d_in[2];   // (B,T)   fp32
    float* out = (float*)d_out;                      // (B,F,T) fp32

    const size_t counts_bytes = (size_t)B * T * sizeof(int);
    const size_t idx_bytes    = (size_t)B * T * K * sizeof(int);

    if (ws_size < counts_bytes + idx_bytes) {
        dim3 g((T + 63) / 64, F, B);
        unpool_dense_fallback<<<g, 64, 0, stream>>>(features, unroll, occ, out);
        return;
    }

    int* counts = (int*)d_ws;
    int* idx    = counts + (size_t)B * T;

    hipMemsetAsync(counts, 0, counts_bytes, stream);

    // Pass 1: (t-tiles, e-chunks, B) = (6, 60, 4) = 1440 blocks x 256 threads
    dim3 g1((T / 4 + 255) / 256, E / ECHUNK, B);
    unpool_scan_kernel<<<g1, 256, 0, stream>>>(unroll, counts, idx);

    // Pass 2: (188, 4) blocks x 256 threads
    dim3 g2((T + 31) / 32, B);
    unpool_gather_kernel<<<g2, 256, 0, stream>>>(features, occ, unroll, counts, idx, out);
}

// Round 2
// 92.233 us; speedup vs baseline: 1.0510x; 1.0510x over previous
//
#include <hip/hip_runtime.h>

#define B 4
#define F 128
#define E 3000
#define T 6000
#define K 16      // max stored nonzeros per output column (Poisson(2) tail: P(>=16) ~ 5e-10)
#define ECHUNK 24 // e-rows per scan block (E = 24 * 125)

// ---------------------------------------------------------------------------
// Pass 1: scan unroll_mat (B,E,T), record nonzero e-indices per (b,t) column.
// 4 e-rows loaded back-to-back before any consumption -> 4 outstanding
// 1KB-per-wave loads, hides ~900cy HBM latency. Binary matrix -> nonzero == 1.
// ---------------------------------------------------------------------------
__global__ void unpool_scan_kernel(const float* __restrict__ unroll,
                                   int* __restrict__ counts,
                                   int* __restrict__ idx) {
    const int b  = blockIdx.z;
    const int e0 = blockIdx.y * ECHUNK;
    const int t4 = (blockIdx.x * blockDim.x + threadIdx.x) * 4;
    if (t4 >= T) return;

    const float* base = unroll + (size_t)b * E * T + t4;
    int* cbase = counts + b * T;
    int* ibase = idx + (size_t)b * T * K;

#define PROC(v, ee)                                                                                   \
    do {                                                                                              \
        if (v.x != 0.0f) { int c = atomicAdd(&cbase[t4 + 0], 1); if (c < K) ibase[(size_t)(t4 + 0) * K + c] = (ee); } \
        if (v.y != 0.0f) { int c = atomicAdd(&cbase[t4 + 1], 1); if (c < K) ibase[(size_t)(t4 + 1) * K + c] = (ee); } \
        if (v.z != 0.0f) { int c = atomicAdd(&cbase[t4 + 2], 1); if (c < K) ibase[(size_t)(t4 + 2) * K + c] = (ee); } \
        if (v.w != 0.0f) { int c = atomicAdd(&cbase[t4 + 3], 1); if (c < K) ibase[(size_t)(t4 + 3) * K + c] = (ee); } \
    } while (0)

#pragma unroll 1
    for (int eg = 0; eg < ECHUNK; eg += 4) {
        const int e = e0 + eg;
        // Issue all four 16B loads before consuming any (ILP latency hiding).
        const float4 v0 = *reinterpret_cast<const float4*>(base + (size_t)(e + 0) * T);
        const float4 v1 = *reinterpret_cast<const float4*>(base + (size_t)(e + 1) * T);
        const float4 v2 = *reinterpret_cast<const float4*>(base + (size_t)(e + 2) * T);
        const float4 v3 = *reinterpret_cast<const float4*>(base + (size_t)(e + 3) * T);
        PROC(v0, e + 0);
        PROC(v1, e + 1);
        PROC(v2, e + 2);
        PROC(v3, e + 3);
    }
#undef PROC
}

// ---------------------------------------------------------------------------
// Pass 2: out[b,f,t] = (1/occ[b,t]) * sum_k features[b,f,e_k]
// 256 threads: t_local = tid & 31 (32 t per block), f_group = tid >> 5 (8
// groups), each thread does 16 f values. Writes coalesced over t.
// ---------------------------------------------------------------------------
__global__ void unpool_gather_kernel(const float* __restrict__ features,
                                     const float* __restrict__ occ,
                                     const float* __restrict__ unroll,
                                     const int* __restrict__ counts,
                                     const int* __restrict__ idx,
                                     float* __restrict__ out) {
    const int b = blockIdx.y;
    const int t = blockIdx.x * 32 + (threadIdx.x & 31);
    const int fg = threadIdx.x >> 5; // 0..7
    if (t >= T) return;

    const int c = counts[b * T + t];
    const float inv = 1.0f / occ[b * T + t];
    const float* fb = features + (size_t)b * F * E;
    float* ob = out + (size_t)b * F * T;

    if (c <= K) {
        // Load index list into registers (fully unrolled -> no scratch).
        // Entries beyond c are stale/garbage but never used (guarded below).
        int es[K];
        const int* ip = idx + ((size_t)b * T + t) * K;
#pragma unroll
        for (int k = 0; k < K; ++k) es[k] = ip[k];

        for (int f = fg; f < F; f += 8) {
            float acc = 0.0f;
#pragma unroll
            for (int k = 0; k < K; ++k) {
                if (k < c) acc += fb[(size_t)f * E + es[k]];
            }
            ob[(size_t)f * T + t] = acc * inv;
        }
    } else {
        // Astronomically rare overflow: exact rescan of this column.
        for (int f = fg; f < F; f += 8) {
            float acc = 0.0f;
            for (int e = 0; e < E; ++e) {
                if (unroll[((size_t)b * E + e) * T + t] != 0.0f)
                    acc += fb[(size_t)f * E + e];
            }
            ob[(size_t)f * T + t] = acc * inv;
        }
    }
}

// ---------------------------------------------------------------------------
// Dense fallback (only if workspace is too small — slow but exact).
// ---------------------------------------------------------------------------
__global__ void unpool_dense_fallback(const float* __restrict__ features,
                                      const float* __restrict__ unroll,
                                      const float* __restrict__ occ,
                                      float* __restrict__ out) {
    const int b = blockIdx.z;
    const int f = blockIdx.y;
    const int t = blockIdx.x * 64 + threadIdx.x;
    if (t >= T) return;
    const float* frow = features + ((size_t)b * F + f) * E;
    const float* ub = unroll + (size_t)b * E * T;
    float acc = 0.0f;
    for (int e = 0; e < E; ++e) acc += frow[e] * ub[(size_t)e * T + t];
    out[((size_t)b * F + f) * T + t] = acc / occ[b * T + t];
}

extern "C" void kernel_launch(void* const* d_in, const int* in_sizes, int n_in,
                              void* d_out, int out_size, void* d_ws, size_t ws_size,
                              hipStream_t stream) {
    const float* features = (const float*)d_in[0];   // (B,F,E) fp32
    const float* unroll   = (const float*)d_in[1];   // (B,E,T) fp32 (binary)
    const float* occ      = (const float*)d_in[2];   // (B,T)   fp32
    float* out = (float*)d_out;                      // (B,F,T) fp32

    const size_t counts_bytes = (size_t)B * T * sizeof(int);
    const size_t idx_bytes    = (size_t)B * T * K * sizeof(int);

    if (ws_size < counts_bytes + idx_bytes) {
        dim3 g((T + 63) / 64, F, B);
        unpool_dense_fallback<<<g, 64, 0, stream>>>(features, unroll, occ, out);
        return;
    }

    int* counts = (int*)d_ws;
    int* idx    = counts + (size_t)B * T;

    hipMemsetAsync(counts, 0, counts_bytes, stream);

    // Pass 1: (t-tiles, e-chunks, B) = (6, 125, 4) = 3000 blocks x 256 threads
    dim3 g1((T / 4 + 255) / 256, E / ECHUNK, B);
    unpool_scan_kernel<<<g1, 256, 0, stream>>>(unroll, counts, idx);

    // Pass 2: (188, 4) blocks x 256 threads
    dim3 g2((T + 31) / 32, B);
    unpool_gather_kernel<<<g2, 256, 0, stream>>>(features, occ, unroll, counts, idx, out);
}

// Round 3
// 90.580 us; speedup vs baseline: 1.0702x; 1.0182x over previous
//
#include <hip/hip_runtime.h>

#define B 4
#define F 128
#define E 3000
#define T 6000
#define K 16       // max stored nonzeros per output column (Poisson(2): P(>=16) ~ 5e-10)
#define ECHUNK 40  // e-rows per scan block (E = 40 * 75)
#define CAP 1024   // LDS match-buffer entries/block (mean ~33, >100 sigma headroom)

// ---------------------------------------------------------------------------
// Pass 1: scan unroll_mat (B,E,T). Matches are appended to an LDS buffer
// (LDS atomic -> lgkmcnt, does NOT drain the vmcnt load pipeline), then
// flushed to global counts/idx once per block. Streaming loop has zero
// global-atomic waits.
// ---------------------------------------------------------------------------
__global__ __launch_bounds__(256) void unpool_scan_kernel(
        const float* __restrict__ unroll,
        int* __restrict__ counts,
        int* __restrict__ idx) {
    __shared__ int ls_cnt;
    __shared__ int2 ls_buf[CAP];

    const int b  = blockIdx.z;
    const int e0 = blockIdx.y * ECHUNK;
    const int t4 = (blockIdx.x * blockDim.x + threadIdx.x) * 4;
    const bool active = (t4 + 3) < T;

    if (threadIdx.x == 0) ls_cnt = 0;
    __syncthreads();

    const float* base = unroll + (size_t)b * E * T + t4;
    int* cbase = counts + b * T;
    int* ibase = idx + (size_t)b * T * K;

    if (active) {
#define ANY_NZ(v) ((__float_as_uint(v.x) | __float_as_uint(v.y) | \
                    __float_as_uint(v.z) | __float_as_uint(v.w)) != 0u)
#define PROC(v, ee)                                                                  \
    do {                                                                             \
        if (ANY_NZ(v)) {                                                             \
            if (v.x != 0.0f) { int s = atomicAdd(&ls_cnt, 1); if (s < CAP) ls_buf[s] = make_int2(t4 + 0, (ee)); } \
            if (v.y != 0.0f) { int s = atomicAdd(&ls_cnt, 1); if (s < CAP) ls_buf[s] = make_int2(t4 + 1, (ee)); } \
            if (v.z != 0.0f) { int s = atomicAdd(&ls_cnt, 1); if (s < CAP) ls_buf[s] = make_int2(t4 + 2, (ee)); } \
            if (v.w != 0.0f) { int s = atomicAdd(&ls_cnt, 1); if (s < CAP) ls_buf[s] = make_int2(t4 + 3, (ee)); } \
        }                                                                            \
    } while (0)
#define LROW(e) (*reinterpret_cast<const float4*>(base + (size_t)(e) * T))

        // Register double-buffer: next 4 rows issue before current 4 consume.
        float4 c0 = LROW(e0 + 0), c1 = LROW(e0 + 1), c2 = LROW(e0 + 2), c3 = LROW(e0 + 3);
#pragma unroll 1
        for (int eg = 0; eg < ECHUNK - 4; eg += 4) {
            const int e = e0 + eg;
            float4 n0 = LROW(e + 4), n1 = LROW(e + 5), n2 = LROW(e + 6), n3 = LROW(e + 7);
            PROC(c0, e + 0);
            PROC(c1, e + 1);
            PROC(c2, e + 2);
            PROC(c3, e + 3);
            c0 = n0; c1 = n1; c2 = n2; c3 = n3;
        }
        const int el = e0 + ECHUNK - 4;
        PROC(c0, el + 0);
        PROC(c1, el + 1);
        PROC(c2, el + 2);
        PROC(c3, el + 3);
#undef LROW
#undef PROC
#undef ANY_NZ
    }

    __syncthreads();
    const int n = ls_cnt;
    if (n <= CAP) {
        // Normal path: flush LDS matches with global atomics (all at once,
        // fully parallel; ~16 entries/block).
        for (int i = threadIdx.x; i < n; i += 256) {
            const int2 p = ls_buf[i];
            const int c = atomicAdd(&cbase[p.x], 1);
            if (c < K) ibase[(size_t)p.x * K + c] = p.y;
        }
    } else if (active) {
        // Statistically impossible overflow: nothing was written globally,
        // so redo this chunk with direct atomics (exact, slow).
        for (int e = e0; e < e0 + ECHUNK; ++e) {
            const float4 v = *reinterpret_cast<const float4*>(base + (size_t)e * T);
            if (v.x != 0.0f) { int c = atomicAdd(&cbase[t4 + 0], 1); if (c < K) ibase[(size_t)(t4 + 0) * K + c] = e; }
            if (v.y != 0.0f) { int c = atomicAdd(&cbase[t4 + 1], 1); if (c < K) ibase[(size_t)(t4 + 1) * K + c] = e; }
            if (v.z != 0.0f) { int c = atomicAdd(&cbase[t4 + 2], 1); if (c < K) ibase[(size_t)(t4 + 2) * K + c] = e; }
            if (v.w != 0.0f) { int c = atomicAdd(&cbase[t4 + 3], 1); if (c < K) ibase[(size_t)(t4 + 3) * K + c] = e; }
        }
    }
}

// ---------------------------------------------------------------------------
// Pass 2: out[b,f,t] = (1/occ[b,t]) * sum_k features[b,f,e_k]
// 256 threads: 32 t per block, 8 f-groups; writes coalesced over t.
// ---------------------------------------------------------------------------
__global__ void unpool_gather_kernel(const float* __restrict__ features,
                                     const float* __restrict__ occ,
                                     const float* __restrict__ unroll,
                                     const int* __restrict__ counts,
                                     const int* __restrict__ idx,
                                     float* __restrict__ out) {
    const int b = blockIdx.y;
    const int t = blockIdx.x * 32 + (threadIdx.x & 31);
    const int fg = threadIdx.x >> 5; // 0..7
    if (t >= T) return;

    const int c = counts[b * T + t];
    const float inv = 1.0f / occ[b * T + t];
    const float* fb = features + (size_t)b * F * E;
    float* ob = out + (size_t)b * F * T;

    if (c <= K) {
        int es[K];
        const int* ip = idx + ((size_t)b * T + t) * K;
#pragma unroll
        for (int k = 0; k < K; ++k) es[k] = ip[k];

        for (int f = fg; f < F; f += 8) {
            float acc = 0.0f;
#pragma unroll
            for (int k = 0; k < K; ++k) {
                if (k < c) acc += fb[(size_t)f * E + es[k]];
            }
            ob[(size_t)f * T + t] = acc * inv;
        }
    } else {
        // Rare overflow of K: exact rescan of this column.
        for (int f = fg; f < F; f += 8) {
            float acc = 0.0f;
            for (int e = 0; e < E; ++e) {
                if (unroll[((size_t)b * E + e) * T + t] != 0.0f)
                    acc += fb[(size_t)f * E + e];
            }
            ob[(size_t)f * T + t] = acc * inv;
        }
    }
}

// ---------------------------------------------------------------------------
// Dense fallback (only if workspace is too small — slow but exact).
// ---------------------------------------------------------------------------
__global__ void unpool_dense_fallback(const float* __restrict__ features,
                                      const float* __restrict__ unroll,
                                      const float* __restrict__ occ,
                                      float* __restrict__ out) {
    const int b = blockIdx.z;
    const int f = blockIdx.y;
    const int t = blockIdx.x * 64 + threadIdx.x;
    if (t >= T) return;
    const float* frow = features + ((size_t)b * F + f) * E;
    const float* ub = unroll + (size_t)b * E * T;
    float acc = 0.0f;
    for (int e = 0; e < E; ++e) acc += frow[e] * ub[(size_t)e * T + t];
    out[((size_t)b * F + f) * T + t] = acc / occ[b * T + t];
}

extern "C" void kernel_launch(void* const* d_in, const int* in_sizes, int n_in,
                              void* d_out, int out_size, void* d_ws, size_t ws_size,
                              hipStream_t stream) {
    const float* features = (const float*)d_in[0];   // (B,F,E) fp32
    const float* unroll   = (const float*)d_in[1];   // (B,E,T) fp32 (binary)
    const float* occ      = (const float*)d_in[2];   // (B,T)   fp32
    float* out = (float*)d_out;                      // (B,F,T) fp32

    const size_t counts_bytes = (size_t)B * T * sizeof(int);
    const size_t idx_bytes    = (size_t)B * T * K * sizeof(int);

    if (ws_size < counts_bytes + idx_bytes) {
        dim3 g((T + 63) / 64, F, B);
        unpool_dense_fallback<<<g, 64, 0, stream>>>(features, unroll, occ, out);
        return;
    }

    int* counts = (int*)d_ws;
    int* idx    = counts + (size_t)B * T;

    hipMemsetAsync(counts, 0, counts_bytes, stream);

    // Pass 1: (t-tiles, e-chunks, B) = (6, 75, 4) = 1800 blocks x 256 threads
    // -> 28 waves/CU, all co-resident in one dispatch round.
    dim3 g1((T / 4 + 255) / 256, E / ECHUNK, B);
    unpool_scan_kernel<<<g1, 256, 0, stream>>>(unroll, counts, idx);

    // Pass 2: (188, 4) blocks x 256 threads
    dim3 g2((T + 31) / 32, B);
    unpool_gather_kernel<<<g2, 256, 0, stream>>>(features, occ, unroll, counts, idx, out);
}

// Round 4
// 84.886 us; speedup vs baseline: 1.1419x; 1.0671x over previous
//
#include <hip/hip_runtime.h>

#define B 4
#define F 128
#define E 3000
#define T 6000
#define K 16       // max stored nonzeros per output column (Poisson(2): P(>=16) ~ 5e-10)
#define ECHUNK 40  // e-rows per scan block (E = 40 * 75)
#define CAP 1024   // LDS match-buffer entries/block (mean ~27, >30 sigma headroom)

typedef unsigned int u32x4 __attribute__((ext_vector_type(4)));

// ---------------------------------------------------------------------------
// Kernel A: feature transpose FT[b][e][f] = features[b][f][e] (6.1 MB).
// Makes the gather's per-edge read a contiguous 512B row instead of a
// 128-element stride-E scatter.
// ---------------------------------------------------------------------------
__global__ __launch_bounds__(256) void feat_transpose_kernel(
        const float* __restrict__ features, float* __restrict__ ft) {
    __shared__ float tile[32][33];
    const int b  = blockIdx.z;
    const int e0 = blockIdx.x * 32;
    const int f0 = blockIdx.y * 32;
    const int tx = threadIdx.x;  // 0..31
    const int ty = threadIdx.y;  // 0..7
    const float* fb = features + (size_t)b * F * E;
    float* ob = ft + (size_t)b * E * F;
#pragma unroll
    for (int j = 0; j < 4; ++j) {
        const int f = f0 + ty + 8 * j;
        const int e = e0 + tx;
        tile[ty + 8 * j][tx] = (e < E) ? fb[(size_t)f * E + e] : 0.0f;
    }
    __syncthreads();
#pragma unroll
    for (int j = 0; j < 4; ++j) {
        const int e = e0 + ty + 8 * j;
        const int f = f0 + tx;
        if (e < E) ob[(size_t)e * F + f] = tile[tx][ty + 8 * j];
    }
}

// ---------------------------------------------------------------------------
// Kernel B: scan unroll_mat (B,E,T). Nontemporal float4 reads (read-once
// stream, don't thrash L2/L3), wave-uniform ballot skip of all-zero rows,
// matches appended to LDS then flushed once per block.
// ---------------------------------------------------------------------------
__global__ __launch_bounds__(256, 8) void unpool_scan_kernel(
        const float* __restrict__ unroll,
        int* __restrict__ counts,
        int* __restrict__ idx) {
    __shared__ int ls_cnt;
    __shared__ int2 ls_buf[CAP];

    const int b  = blockIdx.z;
    const int e0 = blockIdx.y * ECHUNK;
    const int t4 = (blockIdx.x * blockDim.x + threadIdx.x) * 4;
    const bool active = (t4 + 3) < T;

    if (threadIdx.x == 0) ls_cnt = 0;
    __syncthreads();

    const float* base = unroll + (size_t)b * E * T + t4;
    int* cbase = counts + b * T;
    int* ibase = idx + (size_t)b * T * K;

    if (active) {
#define LROW(e) __builtin_nontemporal_load(reinterpret_cast<const u32x4*>(base + (size_t)(e) * T))
#define PROC(v, ee)                                                                  \
    do {                                                                             \
        const unsigned nz = (v[0] | v[1] | v[2] | v[3]);                             \
        if (__ballot(nz != 0u)) {                                                    \
            if (v[0]) { int s = atomicAdd(&ls_cnt, 1); if (s < CAP) ls_buf[s] = make_int2(t4 + 0, (ee)); } \
            if (v[1]) { int s = atomicAdd(&ls_cnt, 1); if (s < CAP) ls_buf[s] = make_int2(t4 + 1, (ee)); } \
            if (v[2]) { int s = atomicAdd(&ls_cnt, 1); if (s < CAP) ls_buf[s] = make_int2(t4 + 2, (ee)); } \
            if (v[3]) { int s = atomicAdd(&ls_cnt, 1); if (s < CAP) ls_buf[s] = make_int2(t4 + 3, (ee)); } \
        }                                                                            \
    } while (0)

        // Register double-buffer: next 4 rows issue before current 4 consume.
        u32x4 c0 = LROW(e0 + 0), c1 = LROW(e0 + 1), c2 = LROW(e0 + 2), c3 = LROW(e0 + 3);
#pragma unroll 1
        for (int eg = 0; eg < ECHUNK - 4; eg += 4) {
            const int e = e0 + eg;
            u32x4 n0 = LROW(e + 4), n1 = LROW(e + 5), n2 = LROW(e + 6), n3 = LROW(e + 7);
            PROC(c0, e + 0);
            PROC(c1, e + 1);
            PROC(c2, e + 2);
            PROC(c3, e + 3);
            c0 = n0; c1 = n1; c2 = n2; c3 = n3;
        }
        const int el = e0 + ECHUNK - 4;
        PROC(c0, el + 0);
        PROC(c1, el + 1);
        PROC(c2, el + 2);
        PROC(c3, el + 3);
#undef PROC
#undef LROW
    }

    __syncthreads();
    const int n = ls_cnt;
    if (n <= CAP) {
        for (int i = threadIdx.x; i < n; i += 256) {
            const int2 p = ls_buf[i];
            const int c = atomicAdd(&cbase[p.x], 1);
            if (c < K) ibase[(size_t)p.x * K + c] = p.y;
        }
    } else if (active) {
        // Statistically impossible overflow: nothing was written globally for
        // this chunk, so redo it with direct atomics (exact, slow).
        for (int e = e0; e < e0 + ECHUNK; ++e) {
            const float4 v = *reinterpret_cast<const float4*>(base + (size_t)e * T);
            if (v.x != 0.0f) { int c = atomicAdd(&cbase[t4 + 0], 1); if (c < K) ibase[(size_t)(t4 + 0) * K + c] = e; }
            if (v.y != 0.0f) { int c = atomicAdd(&cbase[t4 + 1], 1); if (c < K) ibase[(size_t)(t4 + 1) * K + c] = e; }
            if (v.z != 0.0f) { int c = atomicAdd(&cbase[t4 + 2], 1); if (c < K) ibase[(size_t)(t4 + 2) * K + c] = e; }
            if (v.w != 0.0f) { int c = atomicAdd(&cbase[t4 + 3], 1); if (c < K) ibase[(size_t)(t4 + 3) * K + c] = e; }
        }
    }
}

// ---------------------------------------------------------------------------
// Kernel C: gather. Thread owns one t-column and 32 f-values:
// out[b,f,t] = inv * sum_k FT[b, e_k, f..f+3] — contiguous float4 reads per
// matched edge, t-coalesced writes.
// ---------------------------------------------------------------------------
__global__ __launch_bounds__(256) void unpool_gather_kernel(
        const float* __restrict__ ft,
        const float* __restrict__ occ,
        const float* __restrict__ unroll,
        const int* __restrict__ counts,
        const int* __restrict__ idx,
        float* __restrict__ out) {
    const int b  = blockIdx.z;
    const int t  = blockIdx.x * 256 + threadIdx.x;
    const int f0 = blockIdx.y * 32;
    if (t >= T) return;

    const int c = counts[b * T + t];
    const float inv = 1.0f / occ[b * T + t];
    const float* fb = ft + (size_t)b * E * F;
    float* ob = out + (size_t)b * F * T + t;

    if (c <= K) {
        int es[K];
        const int4* ip4 = reinterpret_cast<const int4*>(idx + ((size_t)b * T + t) * K);
#pragma unroll
        for (int q = 0; q < 4; ++q) {
            const int4 v = ip4[q];
            es[4 * q + 0] = v.x; es[4 * q + 1] = v.y;
            es[4 * q + 2] = v.z; es[4 * q + 3] = v.w;
        }
#pragma unroll
        for (int j = 0; j < 8; ++j) {
            const int f = f0 + 4 * j;
            float4 a = make_float4(0.f, 0.f, 0.f, 0.f);
#pragma unroll
            for (int k = 0; k < K; ++k) {
                if (k < c) {
                    const float4 v = *reinterpret_cast<const float4*>(fb + (size_t)es[k] * F + f);
                    a.x += v.x; a.y += v.y; a.z += v.z; a.w += v.w;
                }
            }
            ob[(size_t)(f + 0) * T] = a.x * inv;
            ob[(size_t)(f + 1) * T] = a.y * inv;
            ob[(size_t)(f + 2) * T] = a.z * inv;
            ob[(size_t)(f + 3) * T] = a.w * inv;
        }
    } else {
        // Rare overflow of K: exact rescan of this column.
        for (int j = 0; j < 8; ++j) {
            const int f = f0 + 4 * j;
            float4 a = make_float4(0.f, 0.f, 0.f, 0.f);
            for (int e = 0; e < E; ++e) {
                if (unroll[((size_t)b * E + e) * T + t] != 0.0f) {
                    const float4 v = *reinterpret_cast<const float4*>(fb + (size_t)e * F + f);
                    a.x += v.x; a.y += v.y; a.z += v.z; a.w += v.w;
                }
            }
            ob[(size_t)(f + 0) * T] = a.x * inv;
            ob[(size_t)(f + 1) * T] = a.y * inv;
            ob[(size_t)(f + 2) * T] = a.z * inv;
            ob[(size_t)(f + 3) * T] = a.w * inv;
        }
    }
}

// ---------------------------------------------------------------------------
// Dense fallback (only if workspace is too small — slow but exact).
// ---------------------------------------------------------------------------
__global__ void unpool_dense_fallback(const float* __restrict__ features,
                                      const float* __restrict__ unroll,
                                      const float* __restrict__ occ,
                                      float* __restrict__ out) {
    const int b = blockIdx.z;
    const int f = blockIdx.y;
    const int t = blockIdx.x * 64 + threadIdx.x;
    if (t >= T) return;
    const float* frow = features + ((size_t)b * F + f) * E;
    const float* ub = unroll + (size_t)b * E * T;
    float acc = 0.0f;
    for (int e = 0; e < E; ++e) acc += frow[e] * ub[(size_t)e * T + t];
    out[((size_t)b * F + f) * T + t] = acc / occ[b * T + t];
}

extern "C" void kernel_launch(void* const* d_in, const int* in_sizes, int n_in,
                              void* d_out, int out_size, void* d_ws, size_t ws_size,
                              hipStream_t stream) {
    const float* features = (const float*)d_in[0];   // (B,F,E) fp32
    const float* unroll   = (const float*)d_in[1];   // (B,E,T) fp32 (binary)
    const float* occ      = (const float*)d_in[2];   // (B,T)   fp32
    float* out = (float*)d_out;                      // (B,F,T) fp32

    const size_t counts_bytes = (size_t)B * T * sizeof(int);      // 96 KB
    const size_t idx_bytes    = (size_t)B * T * K * sizeof(int);  // 1.5 MB
    const size_t ft_bytes     = (size_t)B * E * F * sizeof(float);// 6.1 MB

    if (ws_size < counts_bytes + idx_bytes + ft_bytes) {
        dim3 g((T + 63) / 64, F, B);
        unpool_dense_fallback<<<g, 64, 0, stream>>>(features, unroll, occ, out);
        return;
    }

    int*   counts = (int*)d_ws;
    int*   idx    = counts + (size_t)B * T;
    float* ft     = (float*)(idx + (size_t)B * T * K);

    hipMemsetAsync(counts, 0, counts_bytes, stream);

    // A: transpose features -> FT (94, 4, 4) x 256
    dim3 gt((E + 31) / 32, F / 32, B);
    feat_transpose_kernel<<<gt, dim3(32, 8), 0, stream>>>(features, ft);

    // B: scan (6, 75, 4) = 1800 blocks x 256
    dim3 g1((T / 4 + 255) / 256, E / ECHUNK, B);
    unpool_scan_kernel<<<g1, 256, 0, stream>>>(unroll, counts, idx);

    // C: gather (24, 4, 4) = 384 blocks x 256
    dim3 g2((T + 255) / 256, F / 32, B);
    unpool_gather_kernel<<<g2, 256, 0, stream>>>(ft, occ, unroll, counts, idx, out);
}

// Round 5
// 71.364 us; speedup vs baseline: 1.3583x; 1.1895x over previous
//
#include <hip/hip_runtime.h>

#define B 4
#define F 128
#define E 3000
#define T 6000
#define K 16       // max stored nonzeros per output column (Poisson(2): P(>=16) ~ 5e-10)
#define ECHUNK 40  // e-rows per scan block (E = 40 * 75)
#define CAP 1024   // LDS match-buffer entries/block (mean ~27, >30 sigma headroom)

// ---------------------------------------------------------------------------
// Kernel A: feature transpose FT[b][e][f] = features[b][f][e] (6.1 MB),
// plus grid-stride zeroing of counts (removes the separate memset node).
// ---------------------------------------------------------------------------
__global__ __launch_bounds__(256) void feat_transpose_kernel(
        const float* __restrict__ features, float* __restrict__ ft,
        int* __restrict__ counts) {
    __shared__ float tile[32][33];
    const int b  = blockIdx.z;
    const int e0 = blockIdx.x * 32;
    const int f0 = blockIdx.y * 32;
    const int tx = threadIdx.x;  // 0..31
    const int ty = threadIdx.y;  // 0..7

    // Zero counts (B*T = 24000 ints; grid has 385K threads -> one shot).
    {
        const int blk = (blockIdx.z * gridDim.y + blockIdx.y) * gridDim.x + blockIdx.x;
        const int gtid = blk * 256 + ty * 32 + tx;
        if (gtid < B * T) counts[gtid] = 0;
    }

    const float* fb = features + (size_t)b * F * E;
    float* ob = ft + (size_t)b * E * F;
#pragma unroll
    for (int j = 0; j < 4; ++j) {
        const int f = f0 + ty + 8 * j;
        const int e = e0 + tx;
        tile[ty + 8 * j][tx] = (e < E) ? fb[(size_t)f * E + e] : 0.0f;
    }
    __syncthreads();
#pragma unroll
    for (int j = 0; j < 4; ++j) {
        const int e = e0 + ty + 8 * j;
        const int f = f0 + tx;
        if (e < E) ob[(size_t)e * F + f] = tile[tx][ty + 8 * j];
    }
}

// ---------------------------------------------------------------------------
// Kernel B: scan unroll_mat (B,E,T). Plain float4 streaming reads (NT loads
// reverted — unproven, suspected BW loss), wave-uniform ballot skip of
// all-zero rows, matches appended to LDS (lgkmcnt, keeps vmcnt queue deep),
// flushed once per block with global atomics.
// ---------------------------------------------------------------------------
__global__ __launch_bounds__(256) void unpool_scan_kernel(
        const float* __restrict__ unroll,
        int* __restrict__ counts,
        int* __restrict__ idx) {
    __shared__ int ls_cnt;
    __shared__ int2 ls_buf[CAP];

    const int b  = blockIdx.z;
    const int e0 = blockIdx.y * ECHUNK;
    const int t4 = (blockIdx.x * blockDim.x + threadIdx.x) * 4;
    const bool active = (t4 + 3) < T;

    if (threadIdx.x == 0) ls_cnt = 0;
    __syncthreads();

    const float* base = unroll + (size_t)b * E * T + t4;
    int* cbase = counts + b * T;
    int* ibase = idx + (size_t)b * T * K;

    if (active) {
#define LROW(e) (*reinterpret_cast<const float4*>(base + (size_t)(e) * T))
#define ANY_NZ(v) ((__float_as_uint(v.x) | __float_as_uint(v.y) | \
                    __float_as_uint(v.z) | __float_as_uint(v.w)) != 0u)
#define PROC(v, ee)                                                                  \
    do {                                                                             \
        if (__ballot(ANY_NZ(v))) {                                                   \
            if (v.x != 0.0f) { int s = atomicAdd(&ls_cnt, 1); if (s < CAP) ls_buf[s] = make_int2(t4 + 0, (ee)); } \
            if (v.y != 0.0f) { int s = atomicAdd(&ls_cnt, 1); if (s < CAP) ls_buf[s] = make_int2(t4 + 1, (ee)); } \
            if (v.z != 0.0f) { int s = atomicAdd(&ls_cnt, 1); if (s < CAP) ls_buf[s] = make_int2(t4 + 2, (ee)); } \
            if (v.w != 0.0f) { int s = atomicAdd(&ls_cnt, 1); if (s < CAP) ls_buf[s] = make_int2(t4 + 3, (ee)); } \
        }                                                                            \
    } while (0)

        // Register double-buffer: next 4 rows issue before current 4 consume.
        float4 c0 = LROW(e0 + 0), c1 = LROW(e0 + 1), c2 = LROW(e0 + 2), c3 = LROW(e0 + 3);
#pragma unroll 1
        for (int eg = 0; eg < ECHUNK - 4; eg += 4) {
            const int e = e0 + eg;
            float4 n0 = LROW(e + 4), n1 = LROW(e + 5), n2 = LROW(e + 6), n3 = LROW(e + 7);
            PROC(c0, e + 0);
            PROC(c1, e + 1);
            PROC(c2, e + 2);
            PROC(c3, e + 3);
            c0 = n0; c1 = n1; c2 = n2; c3 = n3;
        }
        const int el = e0 + ECHUNK - 4;
        PROC(c0, el + 0);
        PROC(c1, el + 1);
        PROC(c2, el + 2);
        PROC(c3, el + 3);
#undef PROC
#undef ANY_NZ
#undef LROW
    }

    __syncthreads();
    const int n = ls_cnt;
    if (n <= CAP) {
        for (int i = threadIdx.x; i < n; i += 256) {
            const int2 p = ls_buf[i];
            const int c = atomicAdd(&cbase[p.x], 1);
            if (c < K) ibase[(size_t)p.x * K + c] = p.y;
        }
    } else if (active) {
        // Statistically impossible overflow: nothing was written globally for
        // this chunk, so redo it with direct atomics (exact, slow).
        for (int e = e0; e < e0 + ECHUNK; ++e) {
            const float4 v = *reinterpret_cast<const float4*>(base + (size_t)e * T);
            if (v.x != 0.0f) { int c = atomicAdd(&cbase[t4 + 0], 1); if (c < K) ibase[(size_t)(t4 + 0) * K + c] = e; }
            if (v.y != 0.0f) { int c = atomicAdd(&cbase[t4 + 1], 1); if (c < K) ibase[(size_t)(t4 + 1) * K + c] = e; }
            if (v.z != 0.0f) { int c = atomicAdd(&cbase[t4 + 2], 1); if (c < K) ibase[(size_t)(t4 + 2) * K + c] = e; }
            if (v.w != 0.0f) { int c = atomicAdd(&cbase[t4 + 3], 1); if (c < K) ibase[(size_t)(t4 + 3) * K + c] = e; }
        }
    }
}

// ---------------------------------------------------------------------------
// Kernel C: gather. Thread owns one t-column and 16 f-values:
// out[b,f,t] = inv * sum_k FT[b, e_k, f..f+3]. 768 blocks (3/CU). NT stores
// keep FT L2-resident (out is write-once).
// ---------------------------------------------------------------------------
__global__ __launch_bounds__(256) void unpool_gather_kernel(
        const float* __restrict__ ft,
        const float* __restrict__ occ,
        const float* __restrict__ unroll,
        const int* __restrict__ counts,
        const int* __restrict__ idx,
        float* __restrict__ out) {
    const int b  = blockIdx.z;
    const int t  = blockIdx.x * 256 + threadIdx.x;
    const int f0 = blockIdx.y * 16;
    if (t >= T) return;

    const int c = counts[b * T + t];
    const float inv = 1.0f / occ[b * T + t];
    const float* fb = ft + (size_t)b * E * F;
    float* ob = out + (size_t)b * F * T + t;

    if (c <= K) {
        int es[K];
        const int4* ip4 = reinterpret_cast<const int4*>(idx + ((size_t)b * T + t) * K);
#pragma unroll
        for (int q = 0; q < 4; ++q) {
            const int4 v = ip4[q];
            es[4 * q + 0] = v.x; es[4 * q + 1] = v.y;
            es[4 * q + 2] = v.z; es[4 * q + 3] = v.w;
        }
#pragma unroll
        for (int j = 0; j < 4; ++j) {
            const int f = f0 + 4 * j;
            float4 a = make_float4(0.f, 0.f, 0.f, 0.f);
#pragma unroll
            for (int k = 0; k < K; ++k) {
                if (k < c) {
                    const float4 v = *reinterpret_cast<const float4*>(fb + (size_t)es[k] * F + f);
                    a.x += v.x; a.y += v.y; a.z += v.z; a.w += v.w;
                }
            }
            __builtin_nontemporal_store(a.x * inv, ob + (size_t)(f + 0) * T);
            __builtin_nontemporal_store(a.y * inv, ob + (size_t)(f + 1) * T);
            __builtin_nontemporal_store(a.z * inv, ob + (size_t)(f + 2) * T);
            __builtin_nontemporal_store(a.w * inv, ob + (size_t)(f + 3) * T);
        }
    } else {
        // Rare overflow of K: exact rescan of this column.
        for (int j = 0; j < 4; ++j) {
            const int f = f0 + 4 * j;
            float4 a = make_float4(0.f, 0.f, 0.f, 0.f);
            for (int e = 0; e < E; ++e) {
                if (unroll[((size_t)b * E + e) * T + t] != 0.0f) {
                    const float4 v = *reinterpret_cast<const float4*>(fb + (size_t)e * F + f);
                    a.x += v.x; a.y += v.y; a.z += v.z; a.w += v.w;
                }
            }
            ob[(size_t)(f + 0) * T] = a.x * inv;
            ob[(size_t)(f + 1) * T] = a.y * inv;
            ob[(size_t)(f + 2) * T] = a.z * inv;
            ob[(size_t)(f + 3) * T] = a.w * inv;
        }
    }
}

// ---------------------------------------------------------------------------
// Dense fallback (only if workspace is too small — slow but exact).
// ---------------------------------------------------------------------------
__global__ void unpool_dense_fallback(const float* __restrict__ features,
                                      const float* __restrict__ unroll,
                                      const float* __restrict__ occ,
                                      float* __restrict__ out) {
    const int b = blockIdx.z;
    const int f = blockIdx.y;
    const int t = blockIdx.x * 64 + threadIdx.x;
    if (t >= T) return;
    const float* frow = features + ((size_t)b * F + f) * E;
    const float* ub = unroll + (size_t)b * E * T;
    float acc = 0.0f;
    for (int e = 0; e < E; ++e) acc += frow[e] * ub[(size_t)e * T + t];
    out[((size_t)b * F + f) * T + t] = acc / occ[b * T + t];
}

extern "C" void kernel_launch(void* const* d_in, const int* in_sizes, int n_in,
                              void* d_out, int out_size, void* d_ws, size_t ws_size,
                              hipStream_t stream) {
    const float* features = (const float*)d_in[0];   // (B,F,E) fp32
    const float* unroll   = (const float*)d_in[1];   // (B,E,T) fp32 (binary)
    const float* occ      = (const float*)d_in[2];   // (B,T)   fp32
    float* out = (float*)d_out;                      // (B,F,T) fp32

    const size_t counts_bytes = (size_t)B * T * sizeof(int);      // 96 KB
    const size_t idx_bytes    = (size_t)B * T * K * sizeof(int);  // 1.5 MB
    const size_t ft_bytes     = (size_t)B * E * F * sizeof(float);// 6.1 MB

    if (ws_size < counts_bytes + idx_bytes + ft_bytes) {
        dim3 g((T + 63) / 64, F, B);
        unpool_dense_fallback<<<g, 64, 0, stream>>>(features, unroll, occ, out);
        return;
    }

    int*   counts = (int*)d_ws;
    int*   idx    = counts + (size_t)B * T;
    float* ft     = (float*)(idx + (size_t)B * T * K);

    // A: transpose features -> FT, zero counts. (94, 4, 4) x 256
    dim3 gt((E + 31) / 32, F / 32, B);
    feat_transpose_kernel<<<gt, dim3(32, 8), 0, stream>>>(features, ft, counts);

    // B: scan (6, 75, 4) = 1800 blocks x 256
    dim3 g1((T / 4 + 255) / 256, E / ECHUNK, B);
    unpool_scan_kernel<<<g1, 256, 0, stream>>>(unroll, counts, idx);

    // C: gather (24, 8, 4) = 768 blocks x 256
    dim3 g2((T + 255) / 256, F / 16, B);
    unpool_gather_kernel<<<g2, 256, 0, stream>>>(ft, occ, unroll, counts, idx, out);
}